// Round 7
// baseline (472.923 us; speedup 1.0000x reference)
//
#include <hip/hip_runtime.h>

typedef __attribute__((ext_vector_type(8))) short bf16x8;
typedef __attribute__((ext_vector_type(4))) float f32x4;

__device__ __forceinline__ float bf2f(ushort u) {
  union { uint i; float f; } v; v.i = ((uint)u) << 16; return v.f;
}
__device__ __forceinline__ ushort f2bf(float f) {
  union { float f; uint i; } v; v.f = f;
  uint r = (v.i + 0x7FFFu + ((v.i >> 16) & 1u)) >> 16;
  return (ushort)r;
}
__device__ __forceinline__ float blo(uint u) { return __builtin_bit_cast(float, u << 16); }
__device__ __forceinline__ float bhi(uint u) { return __builtin_bit_cast(float, u & 0xffff0000u); }

template <int CTRL>
__device__ __forceinline__ float dppadd(float x) {
  union { float f; int i; } a, b;
  a.f = x;
  b.i = __builtin_amdgcn_update_dpp(0, a.i, CTRL, 0xF, 0xF, true);
  return a.f + b.f;
}
#define DPP_X1 0xB1   // quad_perm [1,0,3,2]
#define DPP_X2 0x4E   // quad_perm [2,3,0,1]
#define DPP_X7 0x141  // row_half_mirror
#define DPP_XF 0x140  // row_mirror

// ---------------- K1: pack weights + zero cnt ----------------

__global__ __launch_bounds__(256) void k_init(
    const float* __restrict__ Wl1, const float* __restrict__ bl1,
    const float* __restrict__ Wr1, const float* __restrict__ br1,
    const float* __restrict__ res1W, const float* __restrict__ res1b,
    const float* __restrict__ Wl2, const float* __restrict__ bl2,
    const float* __restrict__ Wr2, const float* __restrict__ br2,
    const float* __restrict__ res2W, const float* __restrict__ res2b,
    const float* __restrict__ skipW, const float* __restrict__ skipb,
    const float* __restrict__ att1, const float* __restrict__ att2,
    ushort* __restrict__ W1F, float* __restrict__ B1P,
    ushort* __restrict__ W2F, float* __restrict__ B2P,
    float* __restrict__ at6, float* __restrict__ at4, float* __restrict__ at2E,
    int* __restrict__ cnt, int N) {
  const float LOG2E = 1.4426950408889634f;
  int b = blockIdx.x, t = threadIdx.x;
  if (b < 227) {                                 // ---- pack ----
    int tid = b * 256 + t;
    if (tid < 49152) {
      int j = tid & 7, l = (tid >> 3) & 63, ktile = (tid >> 9) & 3, ct = tid >> 11;
      int k = ktile * 32 + ((l >> 4) << 3) + j;
      int n = ct * 16 + (l & 15);
      int sel = n >> 7, jj = n & 127;
      const float* s = sel == 0 ? Wl1 : sel == 1 ? Wr1 : res1W;
      W1F[tid] = f2bf(s[k * 128 + jj]);
    } else if (tid < 57344) {
      int u = tid - 49152;
      int j = u & 7, l = (u >> 3) & 63, ktile = (u >> 9) & 3, ct = u >> 11;
      int k = ktile * 32 + ((l >> 4) << 3) + j;
      int n = ct * 16 + (l & 15);
      int sel = n >> 4, jj = n & 15;
      const float* s = sel == 0 ? Wl2 : sel == 1 ? Wr2 : sel == 2 ? res2W : skipW;
      W2F[u] = f2bf(s[k * 16 + jj]);
    } else if (tid < 57728) {
      int n = tid - 57344;
      int sel = n >> 7, jj = n & 127;
      const float* sb = sel == 0 ? bl1 : sel == 1 ? br1 : res1b;
      B1P[n] = sb[jj];
    } else if (tid < 57792) {
      int n = tid - 57728;
      int sel = n >> 4, jj = n & 15;
      const float* sb = sel == 0 ? bl2 : sel == 1 ? br2 : sel == 2 ? res2b : skipb;
      B2P[n] = sb[jj];
    } else if (tid < 57920) {
      int n = tid - 57792;
      at6[n] = att1[n] * 0.6f * LOG2E;
    } else if (tid < 58048) {
      int n = tid - 57920;
      at4[n] = att1[n] * 0.4f * LOG2E;
    } else if (tid < 58064) {
      int n = tid - 58048;
      at2E[n] = att2[n] * LOG2E;
    }
  } else {                                       // ---- zero cnt ----
    int idx = (b - 227) * 256 + t;
    if (idx < N) cnt[idx] = 0;
  }
}

// ---------------- K2: histogram (4 edges/thread) ----------------

__global__ __launch_bounds__(256) void k_hist(const int* __restrict__ ei, int* __restrict__ cnt, int E) {
  int e4 = (blockIdx.x * 256 + threadIdx.x) * 4;
  if (e4 + 3 < E) {
    int4 d = *(const int4*)&ei[E + e4];
    atomicAdd(&cnt[d.x], 1); atomicAdd(&cnt[d.y], 1);
    atomicAdd(&cnt[d.z], 1); atomicAdd(&cnt[d.w], 1);
  } else {
    for (int e = e4; e < E; ++e) atomicAdd(&cnt[ei[E + e]], 1);
  }
}

// ---------------- K3: per-block sums ----------------

__global__ __launch_bounds__(256) void k_scan1(const int* __restrict__ cnt, int* __restrict__ partial, int n) {
  int i = blockIdx.x * 256 + threadIdx.x;
  int v = (i < n) ? cnt[i] : 0;
  #pragma unroll
  for (int m = 1; m < 64; m <<= 1) v += __shfl_xor(v, m);
  __shared__ int sm[4];
  if ((threadIdx.x & 63) == 0) sm[threadIdx.x >> 6] = v;
  __syncthreads();
  if (threadIdx.x == 0) partial[blockIdx.x] = sm[0] + sm[1] + sm[2] + sm[3];
}

// ---------------- K4: scan with inline lookback ----------------

__global__ __launch_bounds__(256) void k_scan3lb(const int* __restrict__ cnt, const int* __restrict__ partial,
                                                 int* __restrict__ rowptr, int* __restrict__ cursor, int n) {
  int t = threadIdx.x;
  int b = blockIdx.x;
  int acc = 0;
  for (int j = t; j < b; j += 256) acc += partial[j];
  #pragma unroll
  for (int m = 1; m < 64; m <<= 1) acc += __shfl_xor(acc, m);
  __shared__ int sm[4];
  if ((t & 63) == 0) sm[t >> 6] = acc;
  __syncthreads();
  int base = sm[0] + sm[1] + sm[2] + sm[3];
  __shared__ int buf[2][256];
  int i = b * 256 + t;
  int v = (i < n) ? cnt[i] : 0;
  buf[0][t] = v;
  __syncthreads();
  int cur = 0;
  for (int off = 1; off < 256; off <<= 1) {
    int x = buf[cur][t];
    if (t >= off) x += buf[cur][t - off];
    buf[cur ^ 1][t] = x;
    __syncthreads();
    cur ^= 1;
  }
  if (i < n) {
    int incl = buf[cur][t];
    int rp = base + incl - v;
    rowptr[i] = rp;
    cursor[i] = rp;
    if (i == n - 1) rowptr[n] = base + incl;
  }
}

// ---------------- K5: sliced scatter (solo dispatch — needs L2 to itself) ----------------

__global__ __launch_bounds__(256) void k_scatter(const int* __restrict__ ei, int* __restrict__ cursor,
                                                 int* __restrict__ ssrc, int E, int NS) {
  int t = threadIdx.x;
  int base = blockIdx.x * 2048;
  int src[8], dst[8];
  #pragma unroll
  for (int j = 0; j < 8; ++j) {
    int idx = base + j * 256 + t;
    bool ok = idx < E;
    src[j] = ok ? ei[idx] : 0;
    dst[j] = ok ? ei[E + idx] : -1;
  }
  for (int s = 0; s < NS; ++s) {
    #pragma unroll
    for (int j = 0; j < 8; ++j) {
      if ((dst[j] >> 13) == s) {
        int pos = atomicAdd(&cursor[dst[j]], 1);
        ssrc[pos] = src[j];
      }
    }
  }
}

// ---------------- K6: GEMM1 direct from x, LDS-staged coalesced stores ----------------
// Block = 64 rows, all 384 cols. Wave w computes col-tiles w*6..w*6+5.
// A-fragments built from x with guarded float4 loads (no conv pre-pass).
// C staged in LDS (row stride 392 ushort -> 2-way banks only), written as uint4.

__global__ __launch_bounds__(256) void k_gemm1(
    const float* __restrict__ x, const ushort* __restrict__ WF,
    const float* __restrict__ bias,
    ushort* __restrict__ O0, ushort* __restrict__ O1, ushort* __restrict__ O2,
    int M) {
  __shared__ ushort LT[64 * 392];
  int t = threadIdx.x, w = t >> 6, l = t & 63;
  int m0 = blockIdx.x * 64;
  int rql = l & 15, kq = l >> 4;
  // A-fragments: afr[kt*4+rt] = x[m0+rt*16+rql][kt*32+kq*8 .. +8] as bf16x8
  bf16x8 afr[16];
  #pragma unroll
  for (int kt = 0; kt < 4; ++kt) {
    #pragma unroll
    for (int rt = 0; rt < 4; ++rt) {
      int m = m0 + rt * 16 + rql;
      uint4 o = make_uint4(0, 0, 0, 0);
      if (m < M) {
        const float* src = x + (size_t)m * 128 + kt * 32 + kq * 8;
        float4 f0 = *(const float4*)src;
        float4 f1 = *(const float4*)(src + 4);
        o.x = f2bf(f0.x) | ((uint)f2bf(f0.y) << 16);
        o.y = f2bf(f0.z) | ((uint)f2bf(f0.w) << 16);
        o.z = f2bf(f1.x) | ((uint)f2bf(f1.y) << 16);
        o.w = f2bf(f1.z) | ((uint)f2bf(f1.w) << 16);
      }
      afr[kt * 4 + rt] = __builtin_bit_cast(bf16x8, o);
    }
  }
  #pragma unroll
  for (int ct6 = 0; ct6 < 6; ++ct6) {
    int ct = w * 6 + ct6;
    int col = ct * 16 + rql;
    float bv = bias[col];
    f32x4 acc[4] = {};
    #pragma unroll
    for (int kt = 0; kt < 4; ++kt) {
      bf16x8 b = *(const bf16x8*)(WF + ((size_t)((ct * 4 + kt) * 64 + l)) * 8);
      #pragma unroll
      for (int rt = 0; rt < 4; ++rt)
        acc[rt] = __builtin_amdgcn_mfma_f32_16x16x32_bf16(afr[kt * 4 + rt], b, acc[rt], 0, 0, 0);
    }
    #pragma unroll
    for (int rt = 0; rt < 4; ++rt)
      #pragma unroll
      for (int r = 0; r < 4; ++r)
        LT[(rt * 16 + kq * 4 + r) * 392 + col] = f2bf(acc[rt][r] + bv);
  }
  __syncthreads();
  // copy out: 3 arrays x 64 rows x 128 cols (256 B/row), full-line uint4 writes
  #pragma unroll
  for (int a = 0; a < 3; ++a) {
    ushort* O = a == 0 ? O0 : a == 1 ? O1 : O2;
    #pragma unroll
    for (int it = 0; it < 4; ++it) {
      int idx = it * 256 + t;
      int row = idx >> 4, seg = idx & 15;
      int m = m0 + row;
      if (m < M) {
        uint4 v = *(const uint4*)&LT[row * 392 + a * 128 + seg * 8];
        *(uint4*)&O[(size_t)m * 128 + seg * 8] = v;
      }
    }
  }
}

// ---------------- K8: GEMM2 (stride-16 split outputs) ----------------

__global__ __launch_bounds__(256) void k_mfma2(
    const ushort* __restrict__ AF, const ushort* __restrict__ WF,
    const float* __restrict__ bias,
    ushort* __restrict__ O0, ushort* __restrict__ O1,
    ushort* __restrict__ O2, ushort* __restrict__ O3, int M) {
  int w = threadIdx.x >> 6, l = threadIdx.x & 63;
  int m0 = blockIdx.x * 64;
  int c0 = w * 16;
  int ct = c0 >> 4;
  f32x4 acc[4] = {};
  #pragma unroll
  for (int kt = 0; kt < 4; ++kt) {
    bf16x8 b = *(const bf16x8*)(WF + ((size_t)((ct * 4 + kt) * 64 + l)) * 8);
    #pragma unroll
    for (int rt = 0; rt < 4; ++rt) {
      bf16x8 a = *(const bf16x8*)(AF + ((size_t)((blockIdx.x * 16 + rt * 4 + kt) * 64 + l)) * 8);
      acc[rt] = __builtin_amdgcn_mfma_f32_16x16x32_bf16(a, b, acc[rt], 0, 0, 0);
    }
  }
  int col = c0 + (l & 15);
  int arr = col >> 4;
  ushort* O = arr == 0 ? O0 : arr == 1 ? O1 : arr == 2 ? O2 : O3;
  int lcol = col & 15;
  float bv = bias[col];
  int rbase = m0 + ((l >> 4) << 2);
  #pragma unroll
  for (int rt = 0; rt < 4; ++rt) {
    #pragma unroll
    for (int r = 0; r < 4; ++r) {
      int m = rbase + rt * 16 + r;
      if (m < M) O[(size_t)m * 16 + lcol] = f2bf(acc[rt][r] + bv);
    }
  }
}

// ---------------- K7: layer-1 fused, 2 edges per wave ----------------

#define EDGE1B(u, MASKHI)                                              \
  {                                                                    \
    float v0 = blo((u).x), v1 = bhi((u).x);                            \
    float v2 = blo((u).y), v3 = bhi((u).y);                            \
    float m0 = v0 + xr0, m1 = v1 + xr1, m2 = v2 + xr2, m3 = v3 + xr3;  \
    float d = a6.x * m0 + a4.x * __builtin_fabsf(m0);                  \
    d += a6.y * m1; d += a4.y * __builtin_fabsf(m1);                   \
    d += a6.z * m2; d += a4.z * __builtin_fabsf(m2);                   \
    d += a6.w * m3; d += a4.w * __builtin_fabsf(m3);                   \
    d = dppadd<DPP_X1>(d);                                             \
    d = dppadd<DPP_X2>(d);                                             \
    float p = __builtin_amdgcn_exp2f(d);                               \
    if (MASKHI) p = hi ? 0.f : p;                                      \
    acc0 += p * v0; acc1 += p * v1; acc2 += p * v2; acc3 += p * v3;    \
    den += p;                                                          \
  }

__global__ __launch_bounds__(256) void k_gat1(
    const ushort* __restrict__ XLG, const ushort* __restrict__ XR,
    const ushort* __restrict__ RE,
    const float* __restrict__ at6, const float* __restrict__ at4,
    const float* __restrict__ bias1,
    const float* __restrict__ g1, const float* __restrict__ b1,
    const int* __restrict__ rowptr, const int* __restrict__ ssrc,
    ushort* __restrict__ HF, int n) {
  int lane = threadIdx.x & 63;
  int i = blockIdx.x * 4 + (threadIdx.x >> 6);
  if (i >= n) return;
  int l32 = lane & 31;
  bool hi = lane >= 32;
  int fb = l32 * 4;
  size_t rowb = (size_t)i << 8;
  uint2 uxr = *(const uint2*)((const char*)XR + rowb + (fb << 1));
  float xr0 = blo(uxr.x), xr1 = bhi(uxr.x), xr2 = blo(uxr.y), xr3 = bhi(uxr.y);
  float4 a6 = *(const float4*)&at6[fb];
  float4 a4 = *(const float4*)&at4[fb];
  float acc0 = 0.f, acc1 = 0.f, acc2 = 0.f, acc3 = 0.f, den = 0.f;
  {
    uint2 us = *(const uint2*)((const char*)XLG + rowb + (fb << 1));
    EDGE1B(us, true);
  }
  int e0 = __builtin_amdgcn_readfirstlane(rowptr[i]);
  int e1 = __builtin_amdgcn_readfirstlane(rowptr[i + 1]);
  for (int base = e0; base < e1; base += 64) {
    int cnt = e1 - base; if (cnt > 64) cnt = 64;
    int sidx = ssrc[base + (lane < cnt ? lane : cnt - 1)];
    int j = 0;
    for (; j + 4 <= cnt; j += 4) {
      int s0 = __builtin_amdgcn_readlane(sidx, j);
      int s1 = __builtin_amdgcn_readlane(sidx, j + 1);
      int s2 = __builtin_amdgcn_readlane(sidx, j + 2);
      int s3 = __builtin_amdgcn_readlane(sidx, j + 3);
      int rA = hi ? s1 : s0;
      int rB = hi ? s3 : s2;
      uint2 uA = *(const uint2*)((const char*)XLG + ((size_t)(uint)rA << 8) + (fb << 1));
      uint2 uB = *(const uint2*)((const char*)XLG + ((size_t)(uint)rB << 8) + (fb << 1));
      EDGE1B(uA, false);
      EDGE1B(uB, false);
    }
    for (; j + 2 <= cnt; j += 2) {
      int s0 = __builtin_amdgcn_readlane(sidx, j);
      int s1 = __builtin_amdgcn_readlane(sidx, j + 1);
      int r = hi ? s1 : s0;
      uint2 u = *(const uint2*)((const char*)XLG + ((size_t)(uint)r << 8) + (fb << 1));
      EDGE1B(u, false);
    }
    if (j < cnt) {
      int s0 = __builtin_amdgcn_readlane(sidx, j);
      uint2 u = *(const uint2*)((const char*)XLG + ((size_t)(uint)s0 << 8) + (fb << 1));
      EDGE1B(u, true);
    }
  }
  acc0 += __shfl_xor(acc0, 32);
  acc1 += __shfl_xor(acc1, 32);
  acc2 += __shfl_xor(acc2, 32);
  acc3 += __shfl_xor(acc3, 32);
  den  += __shfl_xor(den, 32);
  float inv = 1.f / (den + 1e-16f);
  float4 bv = *(const float4*)&bias1[fb];
  float o0 = acc0 * inv + bv.x, o1 = acc1 * inv + bv.y;
  float o2 = acc2 * inv + bv.z, o3 = acc3 * inv + bv.w;
  float s = o0 + o1 + o2 + o3;
  #pragma unroll
  for (int m = 1; m < 32; m <<= 1) s += __shfl_xor(s, m);
  float mu = s * (1.f / 128.f);
  float d0 = o0 - mu, d1 = o1 - mu, d2 = o2 - mu, d3 = o3 - mu;
  float q = d0 * d0 + d1 * d1 + d2 * d2 + d3 * d3;
  #pragma unroll
  for (int m = 1; m < 32; m <<= 1) q += __shfl_xor(q, m);
  float rstd = rsqrtf(q * (1.f / 128.f) + 1e-5f);
  float4 gg = *(const float4*)&g1[fb];
  float4 bb = *(const float4*)&b1[fb];
  uint2 ur = *(const uint2*)((const char*)RE + rowb + (fb << 1));
  float r0 = blo(ur.x), r1 = bhi(ur.x), r2 = blo(ur.y), r3 = bhi(ur.y);
  float y0 = d0 * rstd * gg.x + bb.x + r0;
  float y1 = d1 * rstd * gg.y + bb.y + r1;
  float y2 = d2 * rstd * gg.z + bb.z + r2;
  float y3 = d3 * rstd * gg.w + bb.w + r3;
  y0 = y0 > 0.f ? y0 : __expf(y0) - 1.f;
  y1 = y1 > 0.f ? y1 : __expf(y1) - 1.f;
  y2 = y2 > 0.f ? y2 : __expf(y2) - 1.f;
  y3 = y3 > 0.f ? y3 : __expf(y3) - 1.f;
  if (!hi) {
    int k8 = l32 >> 1;
    size_t slot = ((size_t)(i >> 4) * 4 + (k8 >> 2)) * 64 + (i & 15) + ((k8 & 3) << 4);
    uint2 o;
    o.x = (uint)f2bf(y0) | ((uint)f2bf(y1) << 16);
    o.y = (uint)f2bf(y2) | ((uint)f2bf(y3) << 16);
    *(uint2*)(HF + slot * 8 + (l32 & 1) * 4) = o;
  }
}

// ---------------- K9: layer-2 fused ----------------

#define EDGE2V(v)                                            \
  {                                                          \
    float m = (v) + xr;                                      \
    float ta = a2 * m;                                       \
    float tb = a2 * __builtin_fabsf(m);                      \
    float tt = 0.6f * ta + 0.4f * tb;                        \
    tt = dppadd<DPP_X1>(tt);                                 \
    tt = dppadd<DPP_X2>(tt);                                 \
    tt = dppadd<DPP_X7>(tt);                                 \
    tt = dppadd<DPP_XF>(tt);                                 \
    float p = __builtin_amdgcn_exp2f(tt);                    \
    acc += p * (v); den += p;                                \
  }

__global__ __launch_bounds__(256) void k_gat2(
    const ushort* __restrict__ XG, const ushort* __restrict__ XRr,
    const ushort* __restrict__ XE, const ushort* __restrict__ XS,
    const float* __restrict__ at2E, const float* __restrict__ bias2,
    const float* __restrict__ g2, const float* __restrict__ b2,
    const int* __restrict__ rowptr, const int* __restrict__ ssrc,
    const float* __restrict__ outW, const float* __restrict__ outB,
    float* __restrict__ Out, int n) {
  __shared__ float sW[1024];
  __shared__ float sB[64];
  int t = threadIdx.x;
  for (int idx = t; idx < 1024; idx += 256) sW[idx] = outW[idx];
  if (t < 64) sB[t] = outB[t];
  __syncthreads();
  int c = t & 15;
  int i = blockIdx.x * 16 + (t >> 4);
  if (i >= n) return;
  size_t ib = (size_t)i << 4;
  float xl = bf2f(XG[ib + c]), xr = bf2f(XRr[ib + c]);
  float resv = bf2f(XE[ib + c]), skipv = bf2f(XS[ib + c]);
  float a2 = at2E[c];
  float acc = 0.f, den = 0.f;
  EDGE2V(xl);
  int e0 = rowptr[i], e1 = rowptr[i + 1];
  int e = e0;
  for (; e + 4 <= e1; e += 4) {
    int s0 = ssrc[e], s1 = ssrc[e + 1], s2 = ssrc[e + 2], s3 = ssrc[e + 3];
    float v0 = bf2f(XG[((size_t)(uint)s0 << 4) + c]);
    float v1 = bf2f(XG[((size_t)(uint)s1 << 4) + c]);
    float v2 = bf2f(XG[((size_t)(uint)s2 << 4) + c]);
    float v3 = bf2f(XG[((size_t)(uint)s3 << 4) + c]);
    EDGE2V(v0); EDGE2V(v1); EDGE2V(v2); EDGE2V(v3);
  }
  for (; e < e1; ++e) {
    int s = ssrc[e];
    float v = bf2f(XG[((size_t)(uint)s << 4) + c]);
    EDGE2V(v);
  }
  float o = acc / (den + 1e-16f) + bias2[c];
  float s = o;
  s = dppadd<DPP_X1>(s); s = dppadd<DPP_X2>(s); s = dppadd<DPP_X7>(s); s = dppadd<DPP_XF>(s);
  float mu = s * (1.f / 16.f);
  float d = o - mu;
  float q = d * d;
  q = dppadd<DPP_X1>(q); q = dppadd<DPP_X2>(q); q = dppadd<DPP_X7>(q); q = dppadd<DPP_XF>(q);
  float rstd = rsqrtf(q * (1.f / 16.f) + 1e-5f);
  float y = d * rstd * g2[c] + b2[c] + resv;
  y = y > 0.f ? y : __expf(y) - 1.f;
  y += skipv;
  float a0 = sB[c * 4 + 0], a1 = sB[c * 4 + 1], ao2 = sB[c * 4 + 2], a3 = sB[c * 4 + 3];
  #pragma unroll
  for (int cc = 0; cc < 16; ++cc) {
    float h = __shfl(y, cc, 16);
    a0 += h * sW[cc * 64 + c * 4 + 0];
    a1 += h * sW[cc * 64 + c * 4 + 1];
    ao2 += h * sW[cc * 64 + c * 4 + 2];
    a3 += h * sW[cc * 64 + c * 4 + 3];
  }
  *(float4*)&Out[(size_t)i * 64 + c * 4] = make_float4(a0, a1, ao2, a3);
}

// ---------------- launch ----------------

extern "C" void kernel_launch(void* const* d_in, const int* in_sizes, int n_in,
                              void* d_out, int out_size, void* d_ws, size_t ws_size,
                              hipStream_t stream) {
  const float* x     = (const float*)d_in[0];
  const int*   ei    = (const int*)d_in[1];
  const float* Wl1   = (const float*)d_in[2];
  const float* bl1   = (const float*)d_in[3];
  const float* Wr1   = (const float*)d_in[4];
  const float* br1   = (const float*)d_in[5];
  const float* att1  = (const float*)d_in[6];
  const float* bias1 = (const float*)d_in[7];
  const float* Wl2   = (const float*)d_in[8];
  const float* bl2   = (const float*)d_in[9];
  const float* Wr2   = (const float*)d_in[10];
  const float* br2   = (const float*)d_in[11];
  const float* att2  = (const float*)d_in[12];
  const float* bias2 = (const float*)d_in[13];
  const float* ln1g  = (const float*)d_in[14];
  const float* ln1b  = (const float*)d_in[15];
  const float* ln2g  = (const float*)d_in[16];
  const float* ln2b  = (const float*)d_in[17];
  const float* res1W = (const float*)d_in[18];
  const float* res1b = (const float*)d_in[19];
  const float* res2W = (const float*)d_in[20];
  const float* res2b = (const float*)d_in[21];
  const float* skipW = (const float*)d_in[22];
  const float* skipb = (const float*)d_in[23];
  const float* outW  = (const float*)d_in[24];
  const float* outb  = (const float*)d_in[25];
  int N = in_sizes[0] / 128;
  int E = in_sizes[1] / 2;
  float* out = (float*)d_out;

  int nblk = (N + 63) / 64;
  int ngrp = nblk * 4;

  // workspace layout (16B aligned)
  ushort* XLG  = (ushort*)d_ws;                      // N*128
  ushort* XR1  = XLG + (size_t)N * 128;              // N*128
  ushort* RE1  = XR1 + (size_t)N * 128;              // N*128
  ushort* HF   = RE1 + (size_t)N * 128;              // ngrp*2048
  ushort* XG2  = HF + (size_t)ngrp * 2048;           // N*16
  ushort* X2R  = XG2 + (size_t)N * 16;
  ushort* X2E  = X2R + (size_t)N * 16;
  ushort* X2S  = X2E + (size_t)N * 16;
  ushort* W1F  = X2S + (size_t)N * 16;               // 49152
  ushort* W2F  = W1F + 49152;                        // 8192
  float*  B1P  = (float*)(W2F + 8192);               // 384
  float*  B2P  = B1P + 384;                          // 64
  float*  at6  = B2P + 64;                           // 128
  float*  at4  = at6 + 128;                          // 128
  float*  at2E = at4 + 128;                          // 16
  int* cnt     = (int*)(at2E + 16);
  int* cursor  = cnt + N;
  int* rowptr  = cursor + N;
  int* ssrc    = rowptr + N + 1;
  int* partial = ssrc + E;

  int nbS = (N + 255) / 256;
  int NS  = ((N - 1) >> 13) + 1;
  int nScat = (E + 2047) / 2048;

  // K1: pack + zero
  k_init<<<227 + nbS, 256, 0, stream>>>(Wl1, bl1, Wr1, br1, res1W, res1b,
                                        Wl2, bl2, Wr2, br2, res2W, res2b, skipW, skipb,
                                        att1, att2, W1F, B1P, W2F, B2P, at6, at4, at2E,
                                        cnt, N);
  // K2: histogram
  k_hist<<<(E + 1023) / 1024, 256, 0, stream>>>(ei, cnt, E);
  // K3/K4: scan
  k_scan1<<<nbS, 256, 0, stream>>>(cnt, partial, N);
  k_scan3lb<<<nbS, 256, 0, stream>>>(cnt, partial, rowptr, cursor, N);
  // K5: scatter (solo — needs L2 for its write window)
  k_scatter<<<nScat, 256, 0, stream>>>(ei, cursor, ssrc, E, NS);
  // K6: GEMM1 from x (no conv pre-pass), coalesced stores
  k_gemm1<<<nblk, 256, 0, stream>>>(x, W1F, B1P, XLG, XR1, RE1, N);
  // K7: layer-1 fused
  k_gat1<<<(N + 3) / 4, 256, 0, stream>>>(XLG, XR1, RE1, at6, at4, bias1, ln1g, ln1b,
                                          rowptr, ssrc, HF, N);
  // K8: GEMM2
  k_mfma2<<<nblk, 256, 0, stream>>>(HF, W2F, B2P, XG2, X2R, X2E, X2S, N);
  // K9: layer-2 fused + output GEMV
  k_gat2<<<(N + 15) / 16, 256, 0, stream>>>(XG2, X2R, X2E, X2S, at2E, bias2, ln2g, ln2b,
                                            rowptr, ssrc, outW, outb, out, N);
}

// Round 8
// 466.183 us; speedup vs baseline: 1.0145x; 1.0145x over previous
//
#include <hip/hip_runtime.h>

typedef __attribute__((ext_vector_type(8))) short bf16x8;
typedef __attribute__((ext_vector_type(4))) float f32x4;

__device__ __forceinline__ float bf2f(ushort u) {
  union { uint i; float f; } v; v.i = ((uint)u) << 16; return v.f;
}
__device__ __forceinline__ ushort f2bf(float f) {
  union { float f; uint i; } v; v.f = f;
  uint r = (v.i + 0x7FFFu + ((v.i >> 16) & 1u)) >> 16;
  return (ushort)r;
}
__device__ __forceinline__ float blo(uint u) { return __builtin_bit_cast(float, u << 16); }
__device__ __forceinline__ float bhi(uint u) { return __builtin_bit_cast(float, u & 0xffff0000u); }

template <int CTRL>
__device__ __forceinline__ float dppadd(float x) {
  union { float f; int i; } a, b;
  a.f = x;
  b.i = __builtin_amdgcn_update_dpp(0, a.i, CTRL, 0xF, 0xF, true);
  return a.f + b.f;
}
#define DPP_X1 0xB1   // quad_perm [1,0,3,2]
#define DPP_X2 0x4E   // quad_perm [2,3,0,1]
#define DPP_X7 0x141  // row_half_mirror
#define DPP_XF 0x140  // row_mirror

// ---------------- K1: pack weights + zero cnt ----------------

__global__ __launch_bounds__(256) void k_init(
    const float* __restrict__ Wl1, const float* __restrict__ bl1,
    const float* __restrict__ Wr1, const float* __restrict__ br1,
    const float* __restrict__ res1W, const float* __restrict__ res1b,
    const float* __restrict__ Wl2, const float* __restrict__ bl2,
    const float* __restrict__ Wr2, const float* __restrict__ br2,
    const float* __restrict__ res2W, const float* __restrict__ res2b,
    const float* __restrict__ skipW, const float* __restrict__ skipb,
    const float* __restrict__ att1, const float* __restrict__ att2,
    ushort* __restrict__ W1F, float* __restrict__ B1P,
    ushort* __restrict__ W2F, float* __restrict__ B2P,
    float* __restrict__ at6, float* __restrict__ at4, float* __restrict__ at2E,
    int* __restrict__ cnt, int N) {
  const float LOG2E = 1.4426950408889634f;
  int b = blockIdx.x, t = threadIdx.x;
  if (b < 227) {                                 // ---- pack ----
    int tid = b * 256 + t;
    if (tid < 49152) {
      int j = tid & 7, l = (tid >> 3) & 63, ktile = (tid >> 9) & 3, ct = tid >> 11;
      int k = ktile * 32 + ((l >> 4) << 3) + j;
      int n = ct * 16 + (l & 15);
      int sel = n >> 7, jj = n & 127;
      const float* s = sel == 0 ? Wl1 : sel == 1 ? Wr1 : res1W;
      W1F[tid] = f2bf(s[k * 128 + jj]);
    } else if (tid < 57344) {
      int u = tid - 49152;
      int j = u & 7, l = (u >> 3) & 63, ktile = (u >> 9) & 3, ct = u >> 11;
      int k = ktile * 32 + ((l >> 4) << 3) + j;
      int n = ct * 16 + (l & 15);
      int sel = n >> 4, jj = n & 15;
      const float* s = sel == 0 ? Wl2 : sel == 1 ? Wr2 : sel == 2 ? res2W : skipW;
      W2F[u] = f2bf(s[k * 16 + jj]);
    } else if (tid < 57728) {
      int n = tid - 57344;
      int sel = n >> 7, jj = n & 127;
      const float* sb = sel == 0 ? bl1 : sel == 1 ? br1 : res1b;
      B1P[n] = sb[jj];
    } else if (tid < 57792) {
      int n = tid - 57728;
      int sel = n >> 4, jj = n & 15;
      const float* sb = sel == 0 ? bl2 : sel == 1 ? br2 : sel == 2 ? res2b : skipb;
      B2P[n] = sb[jj];
    } else if (tid < 57920) {
      int n = tid - 57792;
      at6[n] = att1[n] * 0.6f * LOG2E;
    } else if (tid < 58048) {
      int n = tid - 57920;
      at4[n] = att1[n] * 0.4f * LOG2E;
    } else if (tid < 58064) {
      int n = tid - 58048;
      at2E[n] = att2[n] * LOG2E;
    }
  } else {                                       // ---- zero cnt ----
    int idx = (b - 227) * 256 + t;
    if (idx < N) cnt[idx] = 0;
  }
}

// ---------------- K2: fused histogram + GEMM1 (independent work) ----------------
// blocks [0, nh): histogram (4 edges/thread).
// blocks [nh, nh+nblk): GEMM1 direct from x, LDS-staged coalesced stores.

__global__ __launch_bounds__(256) void k_histgemm(
    const int* __restrict__ ei, int* __restrict__ cnt, int E, int nh,
    const float* __restrict__ x, const ushort* __restrict__ WF,
    const float* __restrict__ bias,
    ushort* __restrict__ O0, ushort* __restrict__ O1, ushort* __restrict__ O2,
    int M) {
  __shared__ ushort LT[64 * 392];
  int b = blockIdx.x, t = threadIdx.x;
  if (b < nh) {
    int e4 = (b * 256 + t) * 4;
    if (e4 + 3 < E) {
      int4 d = *(const int4*)&ei[E + e4];
      atomicAdd(&cnt[d.x], 1); atomicAdd(&cnt[d.y], 1);
      atomicAdd(&cnt[d.z], 1); atomicAdd(&cnt[d.w], 1);
    } else {
      for (int e = e4; e < E; ++e) atomicAdd(&cnt[ei[E + e]], 1);
    }
    return;
  }
  int w = t >> 6, l = t & 63;
  int m0 = (b - nh) * 64;
  int rql = l & 15, kq = l >> 4;
  bf16x8 afr[16];
  #pragma unroll
  for (int kt = 0; kt < 4; ++kt) {
    #pragma unroll
    for (int rt = 0; rt < 4; ++rt) {
      int m = m0 + rt * 16 + rql;
      uint4 o = make_uint4(0, 0, 0, 0);
      if (m < M) {
        const float* src = x + (size_t)m * 128 + kt * 32 + kq * 8;
        float4 f0 = *(const float4*)src;
        float4 f1 = *(const float4*)(src + 4);
        o.x = f2bf(f0.x) | ((uint)f2bf(f0.y) << 16);
        o.y = f2bf(f0.z) | ((uint)f2bf(f0.w) << 16);
        o.z = f2bf(f1.x) | ((uint)f2bf(f1.y) << 16);
        o.w = f2bf(f1.z) | ((uint)f2bf(f1.w) << 16);
      }
      afr[kt * 4 + rt] = __builtin_bit_cast(bf16x8, o);
    }
  }
  #pragma unroll
  for (int ct6 = 0; ct6 < 6; ++ct6) {
    int ct = w * 6 + ct6;
    int col = ct * 16 + rql;
    float bv = bias[col];
    f32x4 acc[4] = {};
    #pragma unroll
    for (int kt = 0; kt < 4; ++kt) {
      bf16x8 bfrag = *(const bf16x8*)(WF + ((size_t)((ct * 4 + kt) * 64 + l)) * 8);
      #pragma unroll
      for (int rt = 0; rt < 4; ++rt)
        acc[rt] = __builtin_amdgcn_mfma_f32_16x16x32_bf16(afr[kt * 4 + rt], bfrag, acc[rt], 0, 0, 0);
    }
    #pragma unroll
    for (int rt = 0; rt < 4; ++rt)
      #pragma unroll
      for (int r = 0; r < 4; ++r)
        LT[(rt * 16 + kq * 4 + r) * 392 + col] = f2bf(acc[rt][r] + bv);
  }
  __syncthreads();
  #pragma unroll
  for (int a = 0; a < 3; ++a) {
    ushort* O = a == 0 ? O0 : a == 1 ? O1 : O2;
    #pragma unroll
    for (int it = 0; it < 4; ++it) {
      int idx = it * 256 + t;
      int row = idx >> 4, seg = idx & 15;
      int m = m0 + row;
      if (m < M) {
        uint4 v = *(const uint4*)&LT[row * 392 + a * 128 + seg * 8];
        *(uint4*)&O[(size_t)m * 128 + seg * 8] = v;
      }
    }
  }
}

// ---------------- K3: per-block sums ----------------

__global__ __launch_bounds__(256) void k_scan1(const int* __restrict__ cnt, int* __restrict__ partial, int n) {
  int i = blockIdx.x * 256 + threadIdx.x;
  int v = (i < n) ? cnt[i] : 0;
  #pragma unroll
  for (int m = 1; m < 64; m <<= 1) v += __shfl_xor(v, m);
  __shared__ int sm[4];
  if ((threadIdx.x & 63) == 0) sm[threadIdx.x >> 6] = v;
  __syncthreads();
  if (threadIdx.x == 0) partial[blockIdx.x] = sm[0] + sm[1] + sm[2] + sm[3];
}

// ---------------- K4: scan with inline lookback ----------------

__global__ __launch_bounds__(256) void k_scan3lb(const int* __restrict__ cnt, const int* __restrict__ partial,
                                                 int* __restrict__ rowptr, int* __restrict__ cursor, int n) {
  int t = threadIdx.x;
  int b = blockIdx.x;
  int acc = 0;
  for (int j = t; j < b; j += 256) acc += partial[j];
  #pragma unroll
  for (int m = 1; m < 64; m <<= 1) acc += __shfl_xor(acc, m);
  __shared__ int sm[4];
  if ((t & 63) == 0) sm[t >> 6] = acc;
  __syncthreads();
  int base = sm[0] + sm[1] + sm[2] + sm[3];
  __shared__ int buf[2][256];
  int i = b * 256 + t;
  int v = (i < n) ? cnt[i] : 0;
  buf[0][t] = v;
  __syncthreads();
  int cur = 0;
  for (int off = 1; off < 256; off <<= 1) {
    int x = buf[cur][t];
    if (t >= off) x += buf[cur][t - off];
    buf[cur ^ 1][t] = x;
    __syncthreads();
    cur ^= 1;
  }
  if (i < n) {
    int incl = buf[cur][t];
    int rp = base + incl - v;
    rowptr[i] = rp;
    cursor[i] = rp;
    if (i == n - 1) rowptr[n] = base + incl;
  }
}

// ---------------- K5: sliced scatter (solo — needs L2 write window) ----------------

__global__ __launch_bounds__(256) void k_scatter(const int* __restrict__ ei, int* __restrict__ cursor,
                                                 int* __restrict__ ssrc, int E, int NS) {
  int t = threadIdx.x;
  int base = blockIdx.x * 2048;
  int src[8], dst[8];
  #pragma unroll
  for (int j = 0; j < 8; ++j) {
    int idx = base + j * 256 + t;
    bool ok = idx < E;
    src[j] = ok ? ei[idx] : 0;
    dst[j] = ok ? ei[E + idx] : -1;
  }
  for (int s = 0; s < NS; ++s) {
    #pragma unroll
    for (int j = 0; j < 8; ++j) {
      if ((dst[j] >> 13) == s) {
        int pos = atomicAdd(&cursor[dst[j]], 1);
        ssrc[pos] = src[j];
      }
    }
  }
}

// ---------------- K7: GEMM2 (stride-16 split outputs) ----------------

__global__ __launch_bounds__(256) void k_mfma2(
    const ushort* __restrict__ AF, const ushort* __restrict__ WF,
    const float* __restrict__ bias,
    ushort* __restrict__ O0, ushort* __restrict__ O1,
    ushort* __restrict__ O2, ushort* __restrict__ O3, int M) {
  int w = threadIdx.x >> 6, l = threadIdx.x & 63;
  int m0 = blockIdx.x * 64;
  int c0 = w * 16;
  int ct = c0 >> 4;
  f32x4 acc[4] = {};
  #pragma unroll
  for (int kt = 0; kt < 4; ++kt) {
    bf16x8 b = *(const bf16x8*)(WF + ((size_t)((ct * 4 + kt) * 64 + l)) * 8);
    #pragma unroll
    for (int rt = 0; rt < 4; ++rt) {
      bf16x8 a = *(const bf16x8*)(AF + ((size_t)((blockIdx.x * 16 + rt * 4 + kt) * 64 + l)) * 8);
      acc[rt] = __builtin_amdgcn_mfma_f32_16x16x32_bf16(a, b, acc[rt], 0, 0, 0);
    }
  }
  int col = c0 + (l & 15);
  int arr = col >> 4;
  ushort* O = arr == 0 ? O0 : arr == 1 ? O1 : arr == 2 ? O2 : O3;
  int lcol = col & 15;
  float bv = bias[col];
  int rbase = m0 + ((l >> 4) << 2);
  #pragma unroll
  for (int rt = 0; rt < 4; ++rt) {
    #pragma unroll
    for (int r = 0; r < 4; ++r) {
      int m = rbase + rt * 16 + r;
      if (m < M) O[(size_t)m * 16 + lcol] = f2bf(acc[rt][r] + bv);
    }
  }
}

// ---------------- K6: layer-1 fused, 2 edges/wave, 8-edge unroll (4 loads in flight) ----------------

#define EDGE1B(u, MASKHI)                                              \
  {                                                                    \
    float v0 = blo((u).x), v1 = bhi((u).x);                            \
    float v2 = blo((u).y), v3 = bhi((u).y);                            \
    float m0 = v0 + xr0, m1 = v1 + xr1, m2 = v2 + xr2, m3 = v3 + xr3;  \
    float d = a6.x * m0 + a4.x * __builtin_fabsf(m0);                  \
    d += a6.y * m1; d += a4.y * __builtin_fabsf(m1);                   \
    d += a6.z * m2; d += a4.z * __builtin_fabsf(m2);                   \
    d += a6.w * m3; d += a4.w * __builtin_fabsf(m3);                   \
    d = dppadd<DPP_X1>(d);                                             \
    d = dppadd<DPP_X2>(d);                                             \
    float p = __builtin_amdgcn_exp2f(d);                               \
    if (MASKHI) p = hi ? 0.f : p;                                      \
    acc0 += p * v0; acc1 += p * v1; acc2 += p * v2; acc3 += p * v3;    \
    den += p;                                                          \
  }

__global__ __launch_bounds__(256) void k_gat1(
    const ushort* __restrict__ XLG, const ushort* __restrict__ XR,
    const ushort* __restrict__ RE,
    const float* __restrict__ at6, const float* __restrict__ at4,
    const float* __restrict__ bias1,
    const float* __restrict__ g1, const float* __restrict__ b1,
    const int* __restrict__ rowptr, const int* __restrict__ ssrc,
    ushort* __restrict__ HF, int n) {
  int lane = threadIdx.x & 63;
  int i = blockIdx.x * 4 + (threadIdx.x >> 6);
  if (i >= n) return;
  int l32 = lane & 31;
  bool hi = lane >= 32;
  int hioff4 = (lane & 32) >> 3;           // 4 for hi half, 0 for lo
  int fbb = l32 << 3;                      // byte offset of this lane's 4 feats
  int fb = l32 * 4;
  size_t rowb = (size_t)i << 8;
  uint2 uxr = *(const uint2*)((const char*)XR + rowb + fbb);
  float xr0 = blo(uxr.x), xr1 = bhi(uxr.x), xr2 = blo(uxr.y), xr3 = bhi(uxr.y);
  float4 a6 = *(const float4*)&at6[fb];
  float4 a4 = *(const float4*)&at4[fb];
  float acc0 = 0.f, acc1 = 0.f, acc2 = 0.f, acc3 = 0.f, den = 0.f;
  {
    uint2 us = *(const uint2*)((const char*)XLG + rowb + fbb);
    EDGE1B(us, true);                      // self loop (half 0 accumulates)
  }
  int e0 = __builtin_amdgcn_readfirstlane(rowptr[i]);
  int e1 = __builtin_amdgcn_readfirstlane(rowptr[i + 1]);
  for (int base = e0; base < e1; base += 64) {
    int cnt = e1 - base; if (cnt > 64) cnt = 64;
    int sidx = ssrc[base + (lane < cnt ? lane : cnt - 1)];
    int j = 0;
    for (; j + 8 <= cnt; j += 8) {
      // lo half takes edge j+2k, hi half edge j+2k+1 via bpermute
      uint o0 = (uint)__builtin_amdgcn_ds_bpermute(((j + 0) << 2) + hioff4, sidx) << 8;
      uint o1 = (uint)__builtin_amdgcn_ds_bpermute(((j + 2) << 2) + hioff4, sidx) << 8;
      uint o2 = (uint)__builtin_amdgcn_ds_bpermute(((j + 4) << 2) + hioff4, sidx) << 8;
      uint o3 = (uint)__builtin_amdgcn_ds_bpermute(((j + 6) << 2) + hioff4, sidx) << 8;
      uint2 u0 = *(const uint2*)((const char*)XLG + o0 + fbb);
      uint2 u1 = *(const uint2*)((const char*)XLG + o1 + fbb);
      uint2 u2 = *(const uint2*)((const char*)XLG + o2 + fbb);
      uint2 u3 = *(const uint2*)((const char*)XLG + o3 + fbb);
      EDGE1B(u0, false); EDGE1B(u1, false); EDGE1B(u2, false); EDGE1B(u3, false);
    }
    for (; j + 2 <= cnt; j += 2) {
      uint o = (uint)__builtin_amdgcn_ds_bpermute((j << 2) + hioff4, sidx) << 8;
      uint2 u = *(const uint2*)((const char*)XLG + o + fbb);
      EDGE1B(u, false);
    }
    if (j < cnt) {                         // odd tail: lo half only (hi reads clamped garbage, masked)
      uint o = (uint)__builtin_amdgcn_ds_bpermute((j << 2) + hioff4, sidx) << 8;
      uint2 u = *(const uint2*)((const char*)XLG + o + fbb);
      EDGE1B(u, true);
    }
  }
  acc0 += __shfl_xor(acc0, 32);
  acc1 += __shfl_xor(acc1, 32);
  acc2 += __shfl_xor(acc2, 32);
  acc3 += __shfl_xor(acc3, 32);
  den  += __shfl_xor(den, 32);
  float inv = 1.f / (den + 1e-16f);
  float4 bv = *(const float4*)&bias1[fb];
  float o0 = acc0 * inv + bv.x, o1 = acc1 * inv + bv.y;
  float o2 = acc2 * inv + bv.z, o3 = acc3 * inv + bv.w;
  float s = o0 + o1 + o2 + o3;
  #pragma unroll
  for (int m = 1; m < 32; m <<= 1) s += __shfl_xor(s, m);
  float mu = s * (1.f / 128.f);
  float d0 = o0 - mu, d1 = o1 - mu, d2 = o2 - mu, d3 = o3 - mu;
  float q = d0 * d0 + d1 * d1 + d2 * d2 + d3 * d3;
  #pragma unroll
  for (int m = 1; m < 32; m <<= 1) q += __shfl_xor(q, m);
  float rstd = rsqrtf(q * (1.f / 128.f) + 1e-5f);
  float4 gg = *(const float4*)&g1[fb];
  float4 bb = *(const float4*)&b1[fb];
  uint2 ur = *(const uint2*)((const char*)RE + rowb + fbb);
  float r0 = blo(ur.x), r1 = bhi(ur.x), r2 = blo(ur.y), r3 = bhi(ur.y);
  float y0 = d0 * rstd * gg.x + bb.x + r0;
  float y1 = d1 * rstd * gg.y + bb.y + r1;
  float y2 = d2 * rstd * gg.z + bb.z + r2;
  float y3 = d3 * rstd * gg.w + bb.w + r3;
  y0 = y0 > 0.f ? y0 : __expf(y0) - 1.f;
  y1 = y1 > 0.f ? y1 : __expf(y1) - 1.f;
  y2 = y2 > 0.f ? y2 : __expf(y2) - 1.f;
  y3 = y3 > 0.f ? y3 : __expf(y3) - 1.f;
  if (!hi) {
    int k8 = l32 >> 1;
    size_t slot = ((size_t)(i >> 4) * 4 + (k8 >> 2)) * 64 + (i & 15) + ((k8 & 3) << 4);
    uint2 o;
    o.x = (uint)f2bf(y0) | ((uint)f2bf(y1) << 16);
    o.y = (uint)f2bf(y2) | ((uint)f2bf(y3) << 16);
    *(uint2*)(HF + slot * 8 + (l32 & 1) * 4) = o;
  }
}

// ---------------- K8: layer-2 fused, 8-edge unroll ----------------

#define EDGE2V(v)                                            \
  {                                                          \
    float m = (v) + xr;                                      \
    float ta = a2 * m;                                       \
    float tb = a2 * __builtin_fabsf(m);                      \
    float tt = 0.6f * ta + 0.4f * tb;                        \
    tt = dppadd<DPP_X1>(tt);                                 \
    tt = dppadd<DPP_X2>(tt);                                 \
    tt = dppadd<DPP_X7>(tt);                                 \
    tt = dppadd<DPP_XF>(tt);                                 \
    float p = __builtin_amdgcn_exp2f(tt);                    \
    acc += p * (v); den += p;                                \
  }

__global__ __launch_bounds__(256) void k_gat2(
    const ushort* __restrict__ XG, const ushort* __restrict__ XRr,
    const ushort* __restrict__ XE, const ushort* __restrict__ XS,
    const float* __restrict__ at2E, const float* __restrict__ bias2,
    const float* __restrict__ g2, const float* __restrict__ b2,
    const int* __restrict__ rowptr, const int* __restrict__ ssrc,
    const float* __restrict__ outW, const float* __restrict__ outB,
    float* __restrict__ Out, int n) {
  __shared__ float sW[1024];
  __shared__ float sB[64];
  int t = threadIdx.x;
  for (int idx = t; idx < 1024; idx += 256) sW[idx] = outW[idx];
  if (t < 64) sB[t] = outB[t];
  __syncthreads();
  int c = t & 15;
  int i = blockIdx.x * 16 + (t >> 4);
  if (i >= n) return;
  size_t ib = (size_t)i << 4;
  float xl = bf2f(XG[ib + c]), xr = bf2f(XRr[ib + c]);
  float resv = bf2f(XE[ib + c]), skipv = bf2f(XS[ib + c]);
  float a2 = at2E[c];
  float acc = 0.f, den = 0.f;
  EDGE2V(xl);
  int e0 = rowptr[i], e1 = rowptr[i + 1];
  int e = e0;
  for (; e + 8 <= e1; e += 8) {
    int s0 = ssrc[e],     s1 = ssrc[e + 1], s2 = ssrc[e + 2], s3 = ssrc[e + 3];
    int s4 = ssrc[e + 4], s5 = ssrc[e + 5], s6 = ssrc[e + 6], s7 = ssrc[e + 7];
    float v0 = bf2f(XG[((size_t)(uint)s0 << 4) + c]);
    float v1 = bf2f(XG[((size_t)(uint)s1 << 4) + c]);
    float v2 = bf2f(XG[((size_t)(uint)s2 << 4) + c]);
    float v3 = bf2f(XG[((size_t)(uint)s3 << 4) + c]);
    float v4 = bf2f(XG[((size_t)(uint)s4 << 4) + c]);
    float v5 = bf2f(XG[((size_t)(uint)s5 << 4) + c]);
    float v6 = bf2f(XG[((size_t)(uint)s6 << 4) + c]);
    float v7 = bf2f(XG[((size_t)(uint)s7 << 4) + c]);
    EDGE2V(v0); EDGE2V(v1); EDGE2V(v2); EDGE2V(v3);
    EDGE2V(v4); EDGE2V(v5); EDGE2V(v6); EDGE2V(v7);
  }
  for (; e < e1; ++e) {
    int s = ssrc[e];
    float v = bf2f(XG[((size_t)(uint)s << 4) + c]);
    EDGE2V(v);
  }
  float o = acc / (den + 1e-16f) + bias2[c];
  float s = o;
  s = dppadd<DPP_X1>(s); s = dppadd<DPP_X2>(s); s = dppadd<DPP_X7>(s); s = dppadd<DPP_XF>(s);
  float mu = s * (1.f / 16.f);
  float d = o - mu;
  float q = d * d;
  q = dppadd<DPP_X1>(q); q = dppadd<DPP_X2>(q); q = dppadd<DPP_X7>(q); q = dppadd<DPP_XF>(q);
  float rstd = rsqrtf(q * (1.f / 16.f) + 1e-5f);
  float y = d * rstd * g2[c] + b2[c] + resv;
  y = y > 0.f ? y : __expf(y) - 1.f;
  y += skipv;
  float a0 = sB[c * 4 + 0], a1 = sB[c * 4 + 1], ao2 = sB[c * 4 + 2], a3 = sB[c * 4 + 3];
  #pragma unroll
  for (int cc = 0; cc < 16; ++cc) {
    float h = __shfl(y, cc, 16);
    a0 += h * sW[cc * 64 + c * 4 + 0];
    a1 += h * sW[cc * 64 + c * 4 + 1];
    ao2 += h * sW[cc * 64 + c * 4 + 2];
    a3 += h * sW[cc * 64 + c * 4 + 3];
  }
  *(float4*)&Out[(size_t)i * 64 + c * 4] = make_float4(a0, a1, ao2, a3);
}

// ---------------- launch ----------------

extern "C" void kernel_launch(void* const* d_in, const int* in_sizes, int n_in,
                              void* d_out, int out_size, void* d_ws, size_t ws_size,
                              hipStream_t stream) {
  const float* x     = (const float*)d_in[0];
  const int*   ei    = (const int*)d_in[1];
  const float* Wl1   = (const float*)d_in[2];
  const float* bl1   = (const float*)d_in[3];
  const float* Wr1   = (const float*)d_in[4];
  const float* br1   = (const float*)d_in[5];
  const float* att1  = (const float*)d_in[6];
  const float* bias1 = (const float*)d_in[7];
  const float* Wl2   = (const float*)d_in[8];
  const float* bl2   = (const float*)d_in[9];
  const float* Wr2   = (const float*)d_in[10];
  const float* br2   = (const float*)d_in[11];
  const float* att2  = (const float*)d_in[12];
  const float* bias2 = (const float*)d_in[13];
  const float* ln1g  = (const float*)d_in[14];
  const float* ln1b  = (const float*)d_in[15];
  const float* ln2g  = (const float*)d_in[16];
  const float* ln2b  = (const float*)d_in[17];
  const float* res1W = (const float*)d_in[18];
  const float* res1b = (const float*)d_in[19];
  const float* res2W = (const float*)d_in[20];
  const float* res2b = (const float*)d_in[21];
  const float* skipW = (const float*)d_in[22];
  const float* skipb = (const float*)d_in[23];
  const float* outW  = (const float*)d_in[24];
  const float* outb  = (const float*)d_in[25];
  int N = in_sizes[0] / 128;
  int E = in_sizes[1] / 2;
  float* out = (float*)d_out;

  int nblk = (N + 63) / 64;
  int ngrp = nblk * 4;

  // workspace layout (16B aligned)
  ushort* XLG  = (ushort*)d_ws;                      // N*128
  ushort* XR1  = XLG + (size_t)N * 128;              // N*128
  ushort* RE1  = XR1 + (size_t)N * 128;              // N*128
  ushort* HF   = RE1 + (size_t)N * 128;              // ngrp*2048
  ushort* XG2  = HF + (size_t)ngrp * 2048;           // N*16
  ushort* X2R  = XG2 + (size_t)N * 16;
  ushort* X2E  = X2R + (size_t)N * 16;
  ushort* X2S  = X2E + (size_t)N * 16;
  ushort* W1F  = X2S + (size_t)N * 16;               // 49152
  ushort* W2F  = W1F + 49152;                        // 8192
  float*  B1P  = (float*)(W2F + 8192);               // 384
  float*  B2P  = B1P + 384;                          // 64
  float*  at6  = B2P + 64;                           // 128
  float*  at4  = at6 + 128;                          // 128
  float*  at2E = at4 + 128;                          // 16
  int* cnt     = (int*)(at2E + 16);
  int* cursor  = cnt + N;
  int* rowptr  = cursor + N;
  int* ssrc    = rowptr + N + 1;
  int* partial = ssrc + E;

  int nbS = (N + 255) / 256;
  int NS  = ((N - 1) >> 13) + 1;
  int nScat = (E + 2047) / 2048;
  int nh = (E + 1023) / 1024;

  // K1: pack + zero
  k_init<<<227 + nbS, 256, 0, stream>>>(Wl1, bl1, Wr1, br1, res1W, res1b,
                                        Wl2, bl2, Wr2, br2, res2W, res2b, skipW, skipb,
                                        att1, att2, W1F, B1P, W2F, B2P, at6, at4, at2E,
                                        cnt, N);
  // K2: histogram + GEMM1 (independent, fused)
  k_histgemm<<<nh + nblk, 256, 0, stream>>>(ei, cnt, E, nh, x, W1F, B1P,
                                            XLG, XR1, RE1, N);
  // K3/K4: scan
  k_scan1<<<nbS, 256, 0, stream>>>(cnt, partial, N);
  k_scan3lb<<<nbS, 256, 0, stream>>>(cnt, partial, rowptr, cursor, N);
  // K5: scatter
  k_scatter<<<nScat, 256, 0, stream>>>(ei, cursor, ssrc, E, NS);
  // K6: layer-1 fused
  k_gat1<<<(N + 3) / 4, 256, 0, stream>>>(XLG, XR1, RE1, at6, at4, bias1, ln1g, ln1b,
                                          rowptr, ssrc, HF, N);
  // K7: GEMM2
  k_mfma2<<<nblk, 256, 0, stream>>>(HF, W2F, B2P, XG2, X2R, X2E, X2S, N);
  // K8: layer-2 fused + output GEMV
  k_gat2<<<(N + 15) / 16, 256, 0, stream>>>(XG2, X2R, X2E, X2S, at2E, bias2, ln2g, ln2b,
                                            rowptr, ssrc, outW, outb, out, N);
}